// Round 5
// baseline (937.215 us; speedup 1.0000x reference)
//
#include <hip/hip_runtime.h>
#include <hip/hip_fp8.h>
#include <math.h>

#define HID 64
#define ANNOT 512
#define NSTEPS 8
#define PCHUNK 4096
#define CSR_CAP 10240

typedef __attribute__((ext_vector_type(8))) short short8_t;
typedef __attribute__((ext_vector_type(16))) float floatx16;

__device__ __forceinline__ float sigmoidf_(float x) { return 1.0f / (1.0f + __expf(-x)); }

__device__ __forceinline__ float bf2f(unsigned short u) {
  return __uint_as_float(((unsigned)u) << 16);
}
__device__ __forceinline__ unsigned short f2bf(float f) {
  unsigned u = __float_as_uint(f);
  unsigned r = ((u >> 16) & 1u) + 0x7fffu;
  return (unsigned short)((u + r) >> 16);
}
__device__ __forceinline__ float bflo(unsigned u) { return __uint_as_float(u << 16); }
__device__ __forceinline__ float bfhi(unsigned u) { return __uint_as_float(u & 0xffff0000u); }
__device__ __forceinline__ unsigned packbf2(float a, float b) {
  return (unsigned)f2bf(a) | ((unsigned)f2bf(b) << 16);
}

// fp8 e4m3 (OCP) helpers — gfx950 HW-accelerated via hip_fp8.h
__device__ __forceinline__ unsigned char f2fp8(float f) {
  __hip_fp8_e4m3 q(f);
  return (unsigned char)q.__x;
}
__device__ __forceinline__ float fp82f(unsigned b) {
  __hip_fp8_e4m3 q;
  q.__x = (__hip_fp8_storage_t)b;
  return (float)q;
}

__device__ __forceinline__ unsigned enc_f(float f) {
  unsigned u = __float_as_uint(f);
  return (f < 0.f) ? ~u : (u | 0x80000000u);
}
__device__ __forceinline__ float dec_f(unsigned u) {
  return (u & 0x80000000u) ? __uint_as_float(u & 0x7FFFFFFFu) : __uint_as_float(~u);
}

// ---------------- reduce GEMM: h[n,64] = x[n,512] @ Wr[512,64] + br  (h bf16 + fp8 shadow) ----------------
__global__ __launch_bounds__(256) void k_reduce(
    const float* __restrict__ x, const float* __restrict__ Wr,
    const float* __restrict__ br, unsigned short* __restrict__ h,
    unsigned char* __restrict__ h8, int n_nodes)
{
  __shared__ float As[32][64];
  __shared__ float Bs[32][64];
  const int tid = threadIdx.x;
  const int tx = tid & 15, ty = tid >> 4;
  const int bm = blockIdx.x * 64;
  float acc[4][4] = {};
  const int mA = tid >> 2;
  const int kA = (tid & 3) * 8;
  const int kB = tid >> 3;
  const int nB = (tid & 7) * 8;
  const bool mvalid = (bm + mA) < n_nodes;
  const size_t rowA = (size_t)(bm + mA) * ANNOT;

  for (int kt = 0; kt < ANNOT; kt += 32) {
    float4 a0 = make_float4(0, 0, 0, 0), a1 = a0;
    if (mvalid) {
      a0 = *(const float4*)(x + rowA + kt + kA);
      a1 = *(const float4*)(x + rowA + kt + kA + 4);
    }
    float4 b0 = *(const float4*)(Wr + (size_t)(kt + kB) * HID + nB);
    float4 b1 = *(const float4*)(Wr + (size_t)(kt + kB) * HID + nB + 4);
    __syncthreads();
    As[kA + 0][mA] = a0.x; As[kA + 1][mA] = a0.y; As[kA + 2][mA] = a0.z; As[kA + 3][mA] = a0.w;
    As[kA + 4][mA] = a1.x; As[kA + 5][mA] = a1.y; As[kA + 6][mA] = a1.z; As[kA + 7][mA] = a1.w;
    *(float4*)&Bs[kB][nB] = b0;
    *(float4*)&Bs[kB][nB + 4] = b1;
    __syncthreads();
#pragma unroll
    for (int k = 0; k < 32; ++k) {
      float4 av = *(const float4*)&As[k][ty * 4];
      float4 bv = *(const float4*)&Bs[k][tx * 4];
      acc[0][0] += av.x * bv.x; acc[0][1] += av.x * bv.y; acc[0][2] += av.x * bv.z; acc[0][3] += av.x * bv.w;
      acc[1][0] += av.y * bv.x; acc[1][1] += av.y * bv.y; acc[1][2] += av.y * bv.z; acc[1][3] += av.y * bv.w;
      acc[2][0] += av.z * bv.x; acc[2][1] += av.z * bv.y; acc[2][2] += av.z * bv.z; acc[2][3] += av.z * bv.w;
      acc[3][0] += av.w * bv.x; acc[3][1] += av.w * bv.y; acc[3][2] += av.w * bv.z; acc[3][3] += av.w * bv.w;
    }
  }
  float4 bias = *(const float4*)(br + tx * 4);
#pragma unroll
  for (int i = 0; i < 4; ++i) {
    int row = bm + ty * 4 + i;
    if (row < n_nodes) {
      float o0 = acc[i][0] + bias.x, o1 = acc[i][1] + bias.y;
      float o2 = acc[i][2] + bias.z, o3 = acc[i][3] + bias.w;
      ushort4 o;
      o.x = f2bf(o0); o.y = f2bf(o1); o.z = f2bf(o2); o.w = f2bf(o3);
      *(ushort4*)(h + (size_t)row * HID + tx * 4) = o;
      unsigned pb = (unsigned)f2fp8(o0) | ((unsigned)f2fp8(o1) << 8) |
                    ((unsigned)f2fp8(o2) << 16) | ((unsigned)f2fp8(o3) << 24);
      *(unsigned*)(h8 + (size_t)row * HID + tx * 4) = pb;
    }
  }
}

// ------------- Bpack precompute: MFMA-fragment layout, bf16 -------------
__global__ void k_bbig(const float* __restrict__ ggc_w, const float* __restrict__ w_ih,
                       const float* __restrict__ w_hh, unsigned short* __restrict__ Bpack)
{
  const int nt = blockIdx.x;   // 0..7
  const int kc = blockIdx.y;   // 0..7
  const int s  = blockIdx.z;   // 0..7
  const int l  = threadIdx.x;  // 0..63
  const int c = nt * 32 + (l & 31);
  const int sec = c >> 6, f = c & 63;
  unsigned short outv[8];
#pragma unroll
  for (int j = 0; j < 8; ++j) {
    int k = kc * 16 + (l >> 5) * 8 + j;
    float v = 0.f;
    if (k < 64) {
      if (sec < 3) {
        const float* Ws = ggc_w + ((size_t)s * 64 + k) * 64;
        const float* wr = w_ih + (size_t)(sec * 64 + f) * 64;
        float a = 0.f;
        for (int q = 0; q < 64; ++q) a += Ws[q] * wr[q];
        v = a;
      }
    } else {
      int k2 = k - 64;
      if (sec == 0)      v = w_hh[(size_t)f * 64 + k2];
      else if (sec == 1) v = w_hh[(size_t)(64 + f) * 64 + k2];
      else if (sec == 3) v = w_hh[(size_t)(128 + f) * 64 + k2];
    }
    outv[j] = f2bf(v);
  }
  unsigned short* dst = Bpack + ((((size_t)s * 8 + kc) * 8 + nt) * 64 + l) * 8;
#pragma unroll
  for (int j = 0; j < 8; ++j) dst[j] = outv[j];
}

// ---------------- CSR build via bucket counting sort ----------------
__global__ __launch_bounds__(256) void k_pcnt(const int* __restrict__ dstv, int E,
                                              int* __restrict__ bukCnt, int nbuk)
{
  __shared__ int lh[256];
  lh[threadIdx.x] = 0;
  __syncthreads();
  for (int e = blockIdx.x * blockDim.x + threadIdx.x; e < E; e += gridDim.x * blockDim.x)
    atomicAdd(&lh[dstv[e] >> 9], 1);
  __syncthreads();
  if (threadIdx.x < nbuk) {
    int v = lh[threadIdx.x];
    if (v) atomicAdd(&bukCnt[threadIdx.x], v);
  }
}

__global__ void k_bscan(const int* __restrict__ bukCnt, int nbuk,
                        int* __restrict__ bukBase, int* __restrict__ bukCur,
                        int* __restrict__ row_ptr, int n_nodes, int E)
{
  if (threadIdx.x == 0 && blockIdx.x == 0) {
    int run = 0;
    for (int b = 0; b < nbuk; ++b) { bukBase[b] = run; bukCur[b] = run; run += bukCnt[b]; }
    bukBase[nbuk] = run;
    row_ptr[n_nodes] = E;
  }
}

__global__ __launch_bounds__(256) void k_part(
    const int* __restrict__ srcv, const int* __restrict__ dstv, int E,
    int* __restrict__ bukCur, uint2* __restrict__ rec, int nbuk)
{
  __shared__ int lhist[256], lexcl[256], lbase[256], lcur[256];
  __shared__ uint2 lrec[PCHUNK];
  __shared__ unsigned char lbuk[PCHUNK];
  const int t = threadIdx.x;
  const int nchunk = (E + PCHUNK - 1) / PCHUNK;
  for (int c = blockIdx.x; c < nchunk; c += gridDim.x) {
    const int e0 = c * PCHUNK;
    const int cnt = min(PCHUNK, E - e0);
    lhist[t] = 0;
    __syncthreads();
    int myS[16], myD[16];
#pragma unroll
    for (int i = 0; i < 16; ++i) {
      int j = t + i * 256;
      myS[i] = -1; myD[i] = 0;
      if (j < cnt) {
        int e = e0 + j;
        myS[i] = srcv[e];
        myD[i] = dstv[e];
        atomicAdd(&lhist[myD[i] >> 9], 1);
      }
    }
    __syncthreads();
    int v = lhist[t];
    lexcl[t] = v;
    __syncthreads();
    for (int d = 1; d < 256; d <<= 1) {
      int u = (t >= d) ? lexcl[t - d] : 0;
      __syncthreads();
      lexcl[t] += u;
      __syncthreads();
    }
    int excl = lexcl[t] - v;
    __syncthreads();
    lexcl[t] = excl;
    lcur[t] = excl;
    if (v > 0) lbase[t] = atomicAdd(&bukCur[t], v);
    __syncthreads();
#pragma unroll
    for (int i = 0; i < 16; ++i) {
      if (myS[i] >= 0) {
        int b = myD[i] >> 9;
        int p = atomicAdd(&lcur[b], 1);
        lrec[p] = make_uint2((unsigned)myS[i], (unsigned)myD[i]);
        lbuk[p] = (unsigned char)b;
      }
    }
    __syncthreads();
    for (int j = t; j < cnt; j += 256) {
      int b = lbuk[j];
      rec[(size_t)lbase[b] + (j - lexcl[b])] = lrec[j];
    }
    __syncthreads();
  }
}

__global__ __launch_bounds__(512) void k_csr(
    const uint2* __restrict__ rec, const int* __restrict__ bukBase,
    int* __restrict__ row_ptr, int* __restrict__ csr_src, int n_nodes)
{
  __shared__ int cnt[512], off[512], cur[512];
  __shared__ int outbuf[CSR_CAP];
  const int b = blockIdx.x;
  const int t = threadIdx.x;
  const int beg = bukBase[b], end = bukBase[b + 1];
  const int m = end - beg;
  const int node0 = b << 9;
  cnt[t] = 0;
  __syncthreads();
  for (int j = t; j < m; j += 512)
    atomicAdd(&cnt[rec[beg + j].y & 511], 1);
  __syncthreads();
  int v = cnt[t];
  off[t] = v;
  __syncthreads();
  for (int d = 1; d < 512; d <<= 1) {
    int u = (t >= d) ? off[t - d] : 0;
    __syncthreads();
    off[t] += u;
    __syncthreads();
  }
  int excl = off[t] - v;
  cur[t] = excl;
  int node = node0 + t;
  if (node < n_nodes) row_ptr[node] = beg + excl;
  __syncthreads();
  for (int j = t; j < m; j += 512) {
    uint2 r = rec[beg + j];
    int p = atomicAdd(&cur[(int)(r.y & 511u)], 1);
    if (p < CSR_CAP) outbuf[p] = (int)r.x;
  }
  __syncthreads();
  for (int j = t; j < m; j += 512)
    csr_src[beg + j] = (j < CSR_CAP) ? outbuf[j] : 0;
}

// ---------------- per-step: CSR gather-sum of fp8 h-shadow (64B rows = 1 line each) ----------------
// wave = 1 node; 8 x 8-lane groups each gather a DIFFERENT edge's 64B fp8 row (8B/lane);
// 2x unroll -> 16 independent single-line gathers in flight. Butterfly-reduce, store bf16 aggr.
__global__ __launch_bounds__(256) void k_aggr(
    const uint2* __restrict__ h8v, const int* __restrict__ row_ptr,
    const int* __restrict__ csr_src, uint4* __restrict__ aggr16, int n_nodes)
{
  const int wid = threadIdx.x >> 6;
  const int lane = threadIdx.x & 63;
  const int grp = lane >> 3;
  const int l8 = lane & 7;
  const int n = blockIdx.x * 4 + wid;
  if (n >= n_nodes) return;
  const int beg = row_ptr[n], end = row_ptr[n + 1];
  float a0 = 0.f, a1 = 0.f, a2 = 0.f, a3 = 0.f, a4 = 0.f, a5 = 0.f, a6 = 0.f, a7 = 0.f;

  int e = beg + grp;
  for (; e + 8 < end; e += 16) {
    int s0 = csr_src[e], s1 = csr_src[e + 8];
    uint2 v0 = h8v[(size_t)s0 * 8 + l8];
    uint2 v1 = h8v[(size_t)s1 * 8 + l8];
    a0 += fp82f(v0.x & 0xffu) + fp82f(v1.x & 0xffu);
    a1 += fp82f((v0.x >> 8) & 0xffu) + fp82f((v1.x >> 8) & 0xffu);
    a2 += fp82f((v0.x >> 16) & 0xffu) + fp82f((v1.x >> 16) & 0xffu);
    a3 += fp82f(v0.x >> 24) + fp82f(v1.x >> 24);
    a4 += fp82f(v0.y & 0xffu) + fp82f(v1.y & 0xffu);
    a5 += fp82f((v0.y >> 8) & 0xffu) + fp82f((v1.y >> 8) & 0xffu);
    a6 += fp82f((v0.y >> 16) & 0xffu) + fp82f((v1.y >> 16) & 0xffu);
    a7 += fp82f(v0.y >> 24) + fp82f(v1.y >> 24);
  }
  if (e < end) {
    int s0 = csr_src[e];
    uint2 v0 = h8v[(size_t)s0 * 8 + l8];
    a0 += fp82f(v0.x & 0xffu);
    a1 += fp82f((v0.x >> 8) & 0xffu);
    a2 += fp82f((v0.x >> 16) & 0xffu);
    a3 += fp82f(v0.x >> 24);
    a4 += fp82f(v0.y & 0xffu);
    a5 += fp82f((v0.y >> 8) & 0xffu);
    a6 += fp82f((v0.y >> 16) & 0xffu);
    a7 += fp82f(v0.y >> 24);
  }

#pragma unroll
  for (int d = 8; d <= 32; d <<= 1) {
    a0 += __shfl_xor(a0, d); a1 += __shfl_xor(a1, d);
    a2 += __shfl_xor(a2, d); a3 += __shfl_xor(a3, d);
    a4 += __shfl_xor(a4, d); a5 += __shfl_xor(a5, d);
    a6 += __shfl_xor(a6, d); a7 += __shfl_xor(a7, d);
  }

  if (lane < 8) {
    uint4 o;
    o.x = packbf2(a0, a1);
    o.y = packbf2(a2, a3);
    o.z = packbf2(a4, a5);
    o.w = packbf2(a6, a7);
    aggr16[(size_t)n * 8 + lane] = o;
  }
}

// ---------------- per-step: MFMA dual-GEMM + GRU gates (in-place bf16 h update + fp8 shadow) ----------------
__global__ __launch_bounds__(256) void k_gru(
    const unsigned short* __restrict__ aggr, unsigned short* __restrict__ h,
    unsigned char* __restrict__ h8,
    const unsigned short* __restrict__ Bpack_s,
    const float* __restrict__ b_ih, const float* __restrict__ b_hh, int n_nodes)
{
  const int wave = threadIdx.x >> 6;
  const int lane = threadIdx.x & 63;
  const int hi = lane >> 5;
  const int l31 = lane & 31;
  const int rbase = blockIdx.x * 128 + wave * 32;
  const int arow = rbase + l31;
  const bool avalid = arow < n_nodes;

  floatx16 acc[8];
#pragma unroll
  for (int nt = 0; nt < 8; ++nt)
#pragma unroll
    for (int j = 0; j < 16; ++j) acc[nt][j] = 0.f;

#pragma unroll
  for (int kc = 0; kc < 8; ++kc) {
    const unsigned short* Asrc = (kc < 4) ? aggr : h;
    short8_t a = {0, 0, 0, 0, 0, 0, 0, 0};
    if (avalid)
      a = *(const short8_t*)(Asrc + (size_t)arow * HID + (kc & 3) * 16 + hi * 8);
    const short8_t* Bb = (const short8_t*)(Bpack_s + (size_t)kc * 8 * 64 * 8);
#pragma unroll
    for (int nt = 0; nt < 8; ++nt) {
      short8_t b = Bb[nt * 64 + lane];
      acc[nt] = __builtin_amdgcn_mfma_f32_32x32x16_bf16(a, b, acc[nt], 0, 0, 0);
    }
  }

  float bi[2][3], bh[2][3];
#pragma unroll
  for (int half = 0; half < 2; ++half) {
    int f = half * 32 + l31;
    bi[half][0] = b_ih[f]; bi[half][1] = b_ih[64 + f]; bi[half][2] = b_ih[128 + f];
    bh[half][0] = b_hh[f]; bh[half][1] = b_hh[64 + f]; bh[half][2] = b_hh[128 + f];
  }
#pragma unroll
  for (int reg = 0; reg < 16; ++reg) {
    int row = rbase + (reg & 3) + 8 * (reg >> 2) + 4 * hi;
    if (row < n_nodes) {
#pragma unroll
      for (int half = 0; half < 2; ++half) {
        int f = half * 32 + l31;
        float rg = sigmoidf_(acc[half][reg] + bi[half][0] + bh[half][0]);
        float zg = sigmoidf_(acc[2 + half][reg] + bi[half][1] + bh[half][1]);
        float ng = tanhf(acc[4 + half][reg] + bi[half][2] + rg * (acc[6 + half][reg] + bh[half][2]));
        size_t idx = (size_t)row * HID + f;
        float hold = bf2f(h[idx]);
        float hnew = (1.f - zg) * ng + zg * hold;
        h[idx] = f2bf(hnew);
        h8[idx] = f2fp8(hnew);
      }
    }
  }
}

// ---------------- pooling ----------------
__global__ __launch_bounds__(256) void k_pool1(
    const unsigned short* __restrict__ h, const int* __restrict__ batch,
    const float* __restrict__ gate_w, const float* __restrict__ gate_b,
    const float* __restrict__ out_w, const float* __restrict__ out_b,
    float* __restrict__ gl, float* __restrict__ f2, unsigned* __restrict__ gmax, int n_nodes)
{
  __shared__ unsigned smax[64];
  if (threadIdx.x < 64) smax[threadIdx.x] = 0u;
  __syncthreads();
  int n = blockIdx.x * blockDim.x + threadIdx.x;
  if (n < n_nodes) {
    float g = gate_b[0], f0 = out_b[0], f1 = out_b[1];
    const ushort4* hr = (const ushort4*)(h + (size_t)n * HID);
#pragma unroll
    for (int q = 0; q < 16; ++q) {
      ushort4 v = hr[q];
      float h0 = bf2f(v.x), h1 = bf2f(v.y), h2 = bf2f(v.z), h3 = bf2f(v.w);
      int k = q * 4;
      g += h0 * gate_w[k] + h1 * gate_w[k + 1] + h2 * gate_w[k + 2] + h3 * gate_w[k + 3];
      f0 += h0 * out_w[2 * k] + h1 * out_w[2 * k + 2] + h2 * out_w[2 * k + 4] + h3 * out_w[2 * k + 6];
      f1 += h0 * out_w[2 * k + 1] + h1 * out_w[2 * k + 3] + h2 * out_w[2 * k + 5] + h3 * out_w[2 * k + 7];
    }
    gl[n] = g;
    f2[2 * n] = f0;
    f2[2 * n + 1] = f1;
    atomicMax(&smax[batch[n]], enc_f(g));
  }
  __syncthreads();
  if (threadIdx.x < 64 && smax[threadIdx.x] != 0u)
    atomicMax(&gmax[threadIdx.x], smax[threadIdx.x]);
}

__global__ __launch_bounds__(256) void k_pool2(
    const float* __restrict__ gl, const float* __restrict__ f2,
    const int* __restrict__ batch, const unsigned* __restrict__ gmax,
    float* __restrict__ acc3, int n_nodes)
{
  __shared__ float sacc[192];
  int t = threadIdx.x;
  if (t < 192) sacc[t] = 0.f;
  __syncthreads();
  int n = blockIdx.x * blockDim.x + t;
  if (n < n_nodes) {
    int b = batch[n];
    float e = expf(gl[n] - dec_f(gmax[b]));
    atomicAdd(&sacc[3 * b + 0], e);
    atomicAdd(&sacc[3 * b + 1], e * f2[2 * n]);
    atomicAdd(&sacc[3 * b + 2], e * f2[2 * n + 1]);
  }
  __syncthreads();
  if (t < 192) {
    float v = sacc[t];
    if (v != 0.f) atomicAdd(&acc3[t], v);
  }
}

__global__ void k_pool3(const float* __restrict__ acc3, float* __restrict__ out, int n_graphs) {
  int g = blockIdx.x * blockDim.x + threadIdx.x;
  if (g < n_graphs) {
    float s = acc3[3 * g] + 1e-16f;
    float p0 = acc3[3 * g + 1] / s, p1 = acc3[3 * g + 2] / s;
    float m = fmaxf(p0, p1);
    float e0 = expf(p0 - m), e1 = expf(p1 - m);
    float d = e0 + e1;
    out[2 * g] = e0 / d;
    out[2 * g + 1] = e1 / d;
  }
}

// ---------------- host ----------------
extern "C" void kernel_launch(void* const* d_in, const int* in_sizes, int n_in,
                              void* d_out, int out_size, void* d_ws, size_t ws_size,
                              hipStream_t stream)
{
  const float* x        = (const float*)d_in[0];
  const int*   edge     = (const int*)d_in[1];
  const int*   batch    = (const int*)d_in[2];
  const float* reduce_w = (const float*)d_in[3];
  const float* reduce_b = (const float*)d_in[4];
  const float* ggc_w    = (const float*)d_in[5];
  const float* w_ih     = (const float*)d_in[6];
  const float* w_hh     = (const float*)d_in[7];
  const float* b_ih     = (const float*)d_in[8];
  const float* b_hh     = (const float*)d_in[9];
  const float* gate_w   = (const float*)d_in[10];
  const float* gate_b   = (const float*)d_in[11];
  const float* out_w    = (const float*)d_in[12];
  const float* out_b    = (const float*)d_in[13];
  float* out = (float*)d_out;

  const int n_nodes  = in_sizes[0] / ANNOT;
  const int E        = in_sizes[1] / 2;
  const int n_graphs = out_size / 2;
  const int* src  = edge;
  const int* dstv = edge + E;
  const int nbuk = (n_nodes + 511) >> 9;

  size_t off = 0;
  auto alloc = [&](size_t bytes) { size_t o = off; off = (off + bytes + 255) & ~(size_t)255; return o; };
  char* w = (char*)d_ws;

  unsigned short* h    = (unsigned short*)(w + alloc((size_t)n_nodes * HID * 2));
  unsigned char*  h8   = (unsigned char*)(w + alloc((size_t)n_nodes * HID));
  unsigned short* aggr = (unsigned short*)(w + alloc((size_t)n_nodes * HID * 2));
  int*   csr_src = (int*)(w + alloc((size_t)E * 4));
  int*   row_ptr = (int*)(w + alloc((size_t)(n_nodes + 1) * 4));
  uint2* rec     = (uint2*)(w + alloc((size_t)E * 8));
  int*   bukCnt  = (int*)(w + alloc((size_t)(nbuk + 1) * 4));
  int*   bukBase = (int*)(w + alloc((size_t)(nbuk + 1) * 4));
  int*   bukCur  = (int*)(w + alloc((size_t)(nbuk + 1) * 4));
  unsigned short* Bpack = (unsigned short*)(w + alloc((size_t)NSTEPS * 8 * 8 * 64 * 8 * 2));
  float* gl      = (float*)(w + alloc((size_t)n_nodes * 4));
  float* f2      = (float*)(w + alloc((size_t)n_nodes * 2 * 4));
  unsigned* gmax = (unsigned*)(w + alloc(256));
  float* acc3    = (float*)(w + alloc(192 * 4));
  (void)ws_size; (void)n_in;

  hipMemsetAsync(bukCnt, 0, (size_t)(nbuk + 1) * 4, stream);
  hipMemsetAsync(gmax, 0, 256, stream);
  hipMemsetAsync(acc3, 0, 192 * 4, stream);

  const int gN64  = (n_nodes + 63) / 64;
  const int gN256 = (n_nodes + 255) / 256;
  const int nchunk = (E + PCHUNK - 1) / PCHUNK;

  k_reduce<<<gN64, 256, 0, stream>>>(x, reduce_w, reduce_b, h, h8, n_nodes);
  k_bbig<<<dim3(8, 8, NSTEPS), 64, 0, stream>>>(ggc_w, w_ih, w_hh, Bpack);

  k_pcnt<<<1024, 256, 0, stream>>>(dstv, E, bukCnt, nbuk);
  k_bscan<<<1, 1, 0, stream>>>(bukCnt, nbuk, bukBase, bukCur, row_ptr, n_nodes, E);
  k_part<<<nchunk, 256, 0, stream>>>(src, dstv, E, bukCur, rec, nbuk);
  k_csr<<<nbuk, 512, 0, stream>>>(rec, bukBase, row_ptr, csr_src, n_nodes);

  for (int s = 0; s < NSTEPS; ++s) {
    k_aggr<<<(n_nodes + 3) / 4, 256, 0, stream>>>((const uint2*)h8, row_ptr, csr_src, (uint4*)aggr, n_nodes);
    k_gru<<<(n_nodes + 127) / 128, 256, 0, stream>>>(aggr, h, h8, Bpack + (size_t)s * 8 * 8 * 64 * 8, b_ih, b_hh, n_nodes);
  }

  k_pool1<<<gN256, 256, 0, stream>>>(h, batch, gate_w, gate_b, out_w, out_b, gl, f2, gmax, n_nodes);
  k_pool2<<<gN256, 256, 0, stream>>>(gl, f2, batch, gmax, acc3, n_nodes);
  k_pool3<<<1, 64, 0, stream>>>(acc3, out, n_graphs);
}

// Round 7
// 868.382 us; speedup vs baseline: 1.0793x; 1.0793x over previous
//
#include <hip/hip_runtime.h>
#include <math.h>

#define HID 64
#define ANNOT 512
#define NSTEPS 8
#define PCHUNK 4096
#define CSR_CAP 10240

typedef __attribute__((ext_vector_type(8))) short short8_t;
typedef __attribute__((ext_vector_type(16))) float floatx16;
typedef __attribute__((ext_vector_type(2))) float floatx2;

__device__ __forceinline__ float sigmoidf_(float x) { return 1.0f / (1.0f + __expf(-x)); }

__device__ __forceinline__ float bf2f(unsigned short u) {
  return __uint_as_float(((unsigned)u) << 16);
}
__device__ __forceinline__ unsigned short f2bf(float f) {
  unsigned u = __float_as_uint(f);
  unsigned r = ((u >> 16) & 1u) + 0x7fffu;
  return (unsigned short)((u + r) >> 16);
}
__device__ __forceinline__ unsigned packbf2(float a, float b) {
  return (unsigned)f2bf(a) | ((unsigned)f2bf(b) << 16);
}

// fp8 e4m3 (OCP) — native gfx950 conversion instructions
__device__ __forceinline__ unsigned char f2fp8(float f) {
  return (unsigned char)__builtin_amdgcn_cvt_pk_fp8_f32(f, 0.f, 0, false);
}

__device__ __forceinline__ unsigned enc_f(float f) {
  unsigned u = __float_as_uint(f);
  return (f < 0.f) ? ~u : (u | 0x80000000u);
}
__device__ __forceinline__ float dec_f(unsigned u) {
  return (u & 0x80000000u) ? __uint_as_float(u & 0x7FFFFFFFu) : __uint_as_float(~u);
}

// ------------- Wpack: reduce_w (512x64 f32) -> bf16 MFMA B-fragments -------------
// Wpack[t=kc*2+nt][lane][j] = Wr[kc*16 + (lane>>5)*8 + j][nt*32 + (lane&31)]
__global__ void k_wpack(const float* __restrict__ Wr, unsigned short* __restrict__ Wpack) {
  const int t = blockIdx.x;    // 0..63
  const int kc = t >> 1, nt = t & 1;
  const int l = threadIdx.x;   // 0..63
  const int c = nt * 32 + (l & 31);
  unsigned short* dst = Wpack + ((size_t)t * 64 + l) * 8;
#pragma unroll
  for (int j = 0; j < 8; ++j) {
    int k = kc * 16 + (l >> 5) * 8 + j;
    dst[j] = f2bf(Wr[(size_t)k * HID + c]);
  }
}

// ---------------- reduce: h[n,64] = x[n,512] @ Wr + br  (MFMA, no LDS; h bf16 + fp8 shadow) ----------------
__global__ __launch_bounds__(256) void k_reduce(
    const float* __restrict__ x, const unsigned short* __restrict__ Wpack,
    const float* __restrict__ br, unsigned short* __restrict__ h,
    unsigned char* __restrict__ h8, int n_nodes)
{
  const int wave = threadIdx.x >> 6;
  const int lane = threadIdx.x & 63;
  const int hi = lane >> 5;
  const int l31 = lane & 31;
  const int rbase = blockIdx.x * 128 + wave * 32;
  const int arow = rbase + l31;
  const bool avalid = arow < n_nodes;
  const float* xrow = x + (size_t)arow * ANNOT + hi * 8;

  floatx16 acc[2];
#pragma unroll
  for (int nt = 0; nt < 2; ++nt)
#pragma unroll
    for (int j = 0; j < 16; ++j) acc[nt][j] = 0.f;

#pragma unroll 4
  for (int kc = 0; kc < 32; ++kc) {
    short8_t a = {0, 0, 0, 0, 0, 0, 0, 0};
    if (avalid) {
      float4 u0 = *(const float4*)(xrow + kc * 16);
      float4 u1 = *(const float4*)(xrow + kc * 16 + 4);
      a[0] = (short)f2bf(u0.x); a[1] = (short)f2bf(u0.y);
      a[2] = (short)f2bf(u0.z); a[3] = (short)f2bf(u0.w);
      a[4] = (short)f2bf(u1.x); a[5] = (short)f2bf(u1.y);
      a[6] = (short)f2bf(u1.z); a[7] = (short)f2bf(u1.w);
    }
    const short8_t* Bb = (const short8_t*)(Wpack + (size_t)kc * 2 * 64 * 8);
#pragma unroll
    for (int nt = 0; nt < 2; ++nt) {
      short8_t b = Bb[nt * 64 + lane];
      acc[nt] = __builtin_amdgcn_mfma_f32_32x32x16_bf16(a, b, acc[nt], 0, 0, 0);
    }
  }

  float bias[2];
  bias[0] = br[l31];
  bias[1] = br[32 + l31];
#pragma unroll
  for (int reg = 0; reg < 16; ++reg) {
    int row = rbase + (reg & 3) + 8 * (reg >> 2) + 4 * hi;
    if (row < n_nodes) {
#pragma unroll
      for (int nt = 0; nt < 2; ++nt) {
        int f = nt * 32 + l31;
        float v = acc[nt][reg] + bias[nt];
        size_t idx = (size_t)row * HID + f;
        h[idx] = f2bf(v);
        h8[idx] = f2fp8(v);
      }
    }
  }
}

// ------------- Bpack precompute: MFMA-fragment layout, bf16 -------------
__global__ void k_bbig(const float* __restrict__ ggc_w, const float* __restrict__ w_ih,
                       const float* __restrict__ w_hh, unsigned short* __restrict__ Bpack)
{
  const int nt = blockIdx.x;   // 0..7
  const int kc = blockIdx.y;   // 0..7
  const int s  = blockIdx.z;   // 0..7
  const int l  = threadIdx.x;  // 0..63
  const int c = nt * 32 + (l & 31);
  const int sec = c >> 6, f = c & 63;
  unsigned short outv[8];
#pragma unroll
  for (int j = 0; j < 8; ++j) {
    int k = kc * 16 + (l >> 5) * 8 + j;
    float v = 0.f;
    if (k < 64) {
      if (sec < 3) {
        const float* Ws = ggc_w + ((size_t)s * 64 + k) * 64;
        const float* wr = w_ih + (size_t)(sec * 64 + f) * 64;
        float a = 0.f;
        for (int q = 0; q < 64; ++q) a += Ws[q] * wr[q];
        v = a;
      }
    } else {
      int k2 = k - 64;
      if (sec == 0)      v = w_hh[(size_t)f * 64 + k2];
      else if (sec == 1) v = w_hh[(size_t)(64 + f) * 64 + k2];
      else if (sec == 3) v = w_hh[(size_t)(128 + f) * 64 + k2];
    }
    outv[j] = f2bf(v);
  }
  unsigned short* dst = Bpack + ((((size_t)s * 8 + kc) * 8 + nt) * 64 + l) * 8;
#pragma unroll
  for (int j = 0; j < 8; ++j) dst[j] = outv[j];
}

// ---------------- CSR build via bucket counting sort ----------------
__global__ __launch_bounds__(256) void k_pcnt(const int* __restrict__ dstv, int E,
                                              int* __restrict__ bukCnt, int nbuk)
{
  __shared__ int lh[256];
  lh[threadIdx.x] = 0;
  __syncthreads();
  for (int e = blockIdx.x * blockDim.x + threadIdx.x; e < E; e += gridDim.x * blockDim.x)
    atomicAdd(&lh[dstv[e] >> 9], 1);
  __syncthreads();
  if (threadIdx.x < nbuk) {
    int v = lh[threadIdx.x];
    if (v) atomicAdd(&bukCnt[threadIdx.x], v);
  }
}

__global__ void k_bscan(const int* __restrict__ bukCnt, int nbuk,
                        int* __restrict__ bukBase, int* __restrict__ bukCur,
                        int* __restrict__ row_ptr, int n_nodes, int E)
{
  if (threadIdx.x == 0 && blockIdx.x == 0) {
    int run = 0;
    for (int b = 0; b < nbuk; ++b) { bukBase[b] = run; bukCur[b] = run; run += bukCnt[b]; }
    bukBase[nbuk] = run;
    row_ptr[n_nodes] = E;
  }
}

__global__ __launch_bounds__(256) void k_part(
    const int* __restrict__ srcv, const int* __restrict__ dstv, int E,
    int* __restrict__ bukCur, uint2* __restrict__ rec, int nbuk)
{
  __shared__ int lhist[256], lexcl[256], lbase[256], lcur[256];
  __shared__ uint2 lrec[PCHUNK];
  __shared__ unsigned char lbuk[PCHUNK];
  const int t = threadIdx.x;
  const int nchunk = (E + PCHUNK - 1) / PCHUNK;
  for (int c = blockIdx.x; c < nchunk; c += gridDim.x) {
    const int e0 = c * PCHUNK;
    const int cnt = min(PCHUNK, E - e0);
    lhist[t] = 0;
    __syncthreads();
    int myS[16], myD[16];
#pragma unroll
    for (int i = 0; i < 16; ++i) {
      int j = t + i * 256;
      myS[i] = -1; myD[i] = 0;
      if (j < cnt) {
        int e = e0 + j;
        myS[i] = srcv[e];
        myD[i] = dstv[e];
        atomicAdd(&lhist[myD[i] >> 9], 1);
      }
    }
    __syncthreads();
    int v = lhist[t];
    lexcl[t] = v;
    __syncthreads();
    for (int d = 1; d < 256; d <<= 1) {
      int u = (t >= d) ? lexcl[t - d] : 0;
      __syncthreads();
      lexcl[t] += u;
      __syncthreads();
    }
    int excl = lexcl[t] - v;
    __syncthreads();
    lexcl[t] = excl;
    lcur[t] = excl;
    if (v > 0) lbase[t] = atomicAdd(&bukCur[t], v);
    __syncthreads();
#pragma unroll
    for (int i = 0; i < 16; ++i) {
      if (myS[i] >= 0) {
        int b = myD[i] >> 9;
        int p = atomicAdd(&lcur[b], 1);
        lrec[p] = make_uint2((unsigned)myS[i], (unsigned)myD[i]);
        lbuk[p] = (unsigned char)b;
      }
    }
    __syncthreads();
    for (int j = t; j < cnt; j += 256) {
      int b = lbuk[j];
      rec[(size_t)lbase[b] + (j - lexcl[b])] = lrec[j];
    }
    __syncthreads();
  }
}

__global__ __launch_bounds__(512) void k_csr(
    const uint2* __restrict__ rec, const int* __restrict__ bukBase,
    int* __restrict__ row_ptr, int* __restrict__ csr_src, int n_nodes)
{
  __shared__ int cnt[512], off[512], cur[512];
  __shared__ int outbuf[CSR_CAP];
  const int b = blockIdx.x;
  const int t = threadIdx.x;
  const int beg = bukBase[b], end = bukBase[b + 1];
  const int m = end - beg;
  const int node0 = b << 9;
  cnt[t] = 0;
  __syncthreads();
  for (int j = t; j < m; j += 512)
    atomicAdd(&cnt[rec[beg + j].y & 511], 1);
  __syncthreads();
  int v = cnt[t];
  off[t] = v;
  __syncthreads();
  for (int d = 1; d < 512; d <<= 1) {
    int u = (t >= d) ? off[t - d] : 0;
    __syncthreads();
    off[t] += u;
    __syncthreads();
  }
  int excl = off[t] - v;
  cur[t] = excl;
  int node = node0 + t;
  if (node < n_nodes) row_ptr[node] = beg + excl;
  __syncthreads();
  for (int j = t; j < m; j += 512) {
    uint2 r = rec[beg + j];
    int p = atomicAdd(&cur[(int)(r.y & 511u)], 1);
    if (p < CSR_CAP) outbuf[p] = (int)r.x;
  }
  __syncthreads();
  for (int j = t; j < m; j += 512)
    csr_src[beg + j] = (j < CSR_CAP) ? outbuf[j] : 0;
}

// ---------------- per-step: CSR gather-sum of fp8 h-shadow (64B rows, native HW decode) ----------------
__global__ __launch_bounds__(256) void k_aggr(
    const uint2* __restrict__ h8v, const int* __restrict__ row_ptr,
    const int* __restrict__ csr_src, uint4* __restrict__ aggr16, int n_nodes)
{
  const int wid = threadIdx.x >> 6;
  const int lane = threadIdx.x & 63;
  const int grp = lane >> 3;
  const int l8 = lane & 7;
  const int n = blockIdx.x * 4 + wid;
  if (n >= n_nodes) return;
  const int beg = row_ptr[n], end = row_ptr[n + 1];
  float a0 = 0.f, a1 = 0.f, a2 = 0.f, a3 = 0.f, a4 = 0.f, a5 = 0.f, a6 = 0.f, a7 = 0.f;

  int e = beg + grp;
  for (; e + 8 < end; e += 16) {
    int s0 = csr_src[e], s1 = csr_src[e + 8];
    uint2 v0 = h8v[(size_t)s0 * 8 + l8];
    uint2 v1 = h8v[(size_t)s1 * 8 + l8];
    floatx2 p0 = __builtin_amdgcn_cvt_pk_f32_fp8(v0.x, false);
    floatx2 p1 = __builtin_amdgcn_cvt_pk_f32_fp8(v0.x, true);
    floatx2 p2 = __builtin_amdgcn_cvt_pk_f32_fp8(v0.y, false);
    floatx2 p3 = __builtin_amdgcn_cvt_pk_f32_fp8(v0.y, true);
    floatx2 q0 = __builtin_amdgcn_cvt_pk_f32_fp8(v1.x, false);
    floatx2 q1 = __builtin_amdgcn_cvt_pk_f32_fp8(v1.x, true);
    floatx2 q2 = __builtin_amdgcn_cvt_pk_f32_fp8(v1.y, false);
    floatx2 q3 = __builtin_amdgcn_cvt_pk_f32_fp8(v1.y, true);
    a0 += p0[0] + q0[0]; a1 += p0[1] + q0[1];
    a2 += p1[0] + q1[0]; a3 += p1[1] + q1[1];
    a4 += p2[0] + q2[0]; a5 += p2[1] + q2[1];
    a6 += p3[0] + q3[0]; a7 += p3[1] + q3[1];
  }
  if (e < end) {
    int s0 = csr_src[e];
    uint2 v0 = h8v[(size_t)s0 * 8 + l8];
    floatx2 p0 = __builtin_amdgcn_cvt_pk_f32_fp8(v0.x, false);
    floatx2 p1 = __builtin_amdgcn_cvt_pk_f32_fp8(v0.x, true);
    floatx2 p2 = __builtin_amdgcn_cvt_pk_f32_fp8(v0.y, false);
    floatx2 p3 = __builtin_amdgcn_cvt_pk_f32_fp8(v0.y, true);
    a0 += p0[0]; a1 += p0[1];
    a2 += p1[0]; a3 += p1[1];
    a4 += p2[0]; a5 += p2[1];
    a6 += p3[0]; a7 += p3[1];
  }

#pragma unroll
  for (int d = 8; d <= 32; d <<= 1) {
    a0 += __shfl_xor(a0, d); a1 += __shfl_xor(a1, d);
    a2 += __shfl_xor(a2, d); a3 += __shfl_xor(a3, d);
    a4 += __shfl_xor(a4, d); a5 += __shfl_xor(a5, d);
    a6 += __shfl_xor(a6, d); a7 += __shfl_xor(a7, d);
  }

  if (lane < 8) {
    uint4 o;
    o.x = packbf2(a0, a1);
    o.y = packbf2(a2, a3);
    o.z = packbf2(a4, a5);
    o.w = packbf2(a6, a7);
    aggr16[(size_t)n * 8 + lane] = o;
  }
}

// ---------------- per-step: MFMA dual-GEMM + GRU gates (in-place bf16 h update + fp8 shadow) ----------------
__global__ __launch_bounds__(256) void k_gru(
    const unsigned short* __restrict__ aggr, unsigned short* __restrict__ h,
    unsigned char* __restrict__ h8,
    const unsigned short* __restrict__ Bpack_s,
    const float* __restrict__ b_ih, const float* __restrict__ b_hh, int n_nodes)
{
  const int wave = threadIdx.x >> 6;
  const int lane = threadIdx.x & 63;
  const int hi = lane >> 5;
  const int l31 = lane & 31;
  const int rbase = blockIdx.x * 128 + wave * 32;
  const int arow = rbase + l31;
  const bool avalid = arow < n_nodes;

  floatx16 acc[8];
#pragma unroll
  for (int nt = 0; nt < 8; ++nt)
#pragma unroll
    for (int j = 0; j < 16; ++j) acc[nt][j] = 0.f;

#pragma unroll
  for (int kc = 0; kc < 8; ++kc) {
    const unsigned short* Asrc = (kc < 4) ? aggr : h;
    short8_t a = {0, 0, 0, 0, 0, 0, 0, 0};
    if (avalid)
      a = *(const short8_t*)(Asrc + (size_t)arow * HID + (kc & 3) * 16 + hi * 8);
    const short8_t* Bb = (const short8_t*)(Bpack_s + (size_t)kc * 8 * 64 * 8);
#pragma unroll
    for (int nt = 0; nt < 8; ++nt) {
      short8_t b = Bb[nt * 64 + lane];
      acc[nt] = __builtin_amdgcn_mfma_f32_32x32x16_bf16(a, b, acc[nt], 0, 0, 0);
    }
  }

  float bi[2][3], bh[2][3];
#pragma unroll
  for (int half = 0; half < 2; ++half) {
    int f = half * 32 + l31;
    bi[half][0] = b_ih[f]; bi[half][1] = b_ih[64 + f]; bi[half][2] = b_ih[128 + f];
    bh[half][0] = b_hh[f]; bh[half][1] = b_hh[64 + f]; bh[half][2] = b_hh[128 + f];
  }
#pragma unroll
  for (int reg = 0; reg < 16; ++reg) {
    int row = rbase + (reg & 3) + 8 * (reg >> 2) + 4 * hi;
    if (row < n_nodes) {
#pragma unroll
      for (int half = 0; half < 2; ++half) {
        int f = half * 32 + l31;
        float rg = sigmoidf_(acc[half][reg] + bi[half][0] + bh[half][0]);
        float zg = sigmoidf_(acc[2 + half][reg] + bi[half][1] + bh[half][1]);
        float ng = tanhf(acc[4 + half][reg] + bi[half][2] + rg * (acc[6 + half][reg] + bh[half][2]));
        size_t idx = (size_t)row * HID + f;
        float hold = bf2f(h[idx]);
        float hnew = (1.f - zg) * ng + zg * hold;
        h[idx] = f2bf(hnew);
        h8[idx] = f2fp8(hnew);
      }
    }
  }
}

// ---------------- pooling ----------------
__global__ __launch_bounds__(256) void k_pool1(
    const unsigned short* __restrict__ h, const int* __restrict__ batch,
    const float* __restrict__ gate_w, const float* __restrict__ gate_b,
    const float* __restrict__ out_w, const float* __restrict__ out_b,
    float* __restrict__ gl, float* __restrict__ f2, unsigned* __restrict__ gmax, int n_nodes)
{
  __shared__ unsigned smax[64];
  if (threadIdx.x < 64) smax[threadIdx.x] = 0u;
  __syncthreads();
  int n = blockIdx.x * blockDim.x + threadIdx.x;
  if (n < n_nodes) {
    float g = gate_b[0], f0 = out_b[0], f1 = out_b[1];
    const ushort4* hr = (const ushort4*)(h + (size_t)n * HID);
#pragma unroll
    for (int q = 0; q < 16; ++q) {
      ushort4 v = hr[q];
      float h0 = bf2f(v.x), h1 = bf2f(v.y), h2 = bf2f(v.z), h3 = bf2f(v.w);
      int k = q * 4;
      g += h0 * gate_w[k] + h1 * gate_w[k + 1] + h2 * gate_w[k + 2] + h3 * gate_w[k + 3];
      f0 += h0 * out_w[2 * k] + h1 * out_w[2 * k + 2] + h2 * out_w[2 * k + 4] + h3 * out_w[2 * k + 6];
      f1 += h0 * out_w[2 * k + 1] + h1 * out_w[2 * k + 3] + h2 * out_w[2 * k + 5] + h3 * out_w[2 * k + 7];
    }
    gl[n] = g;
    f2[2 * n] = f0;
    f2[2 * n + 1] = f1;
    atomicMax(&smax[batch[n]], enc_f(g));
  }
  __syncthreads();
  if (threadIdx.x < 64 && smax[threadIdx.x] != 0u)
    atomicMax(&gmax[threadIdx.x], smax[threadIdx.x]);
}

__global__ __launch_bounds__(256) void k_pool2(
    const float* __restrict__ gl, const float* __restrict__ f2,
    const int* __restrict__ batch, const unsigned* __restrict__ gmax,
    float* __restrict__ acc3, int n_nodes)
{
  __shared__ float sacc[192];
  int t = threadIdx.x;
  if (t < 192) sacc[t] = 0.f;
  __syncthreads();
  int n = blockIdx.x * blockDim.x + t;
  if (n < n_nodes) {
    int b = batch[n];
    float e = expf(gl[n] - dec_f(gmax[b]));
    atomicAdd(&sacc[3 * b + 0], e);
    atomicAdd(&sacc[3 * b + 1], e * f2[2 * n]);
    atomicAdd(&sacc[3 * b + 2], e * f2[2 * n + 1]);
  }
  __syncthreads();
  if (t < 192) {
    float v = sacc[t];
    if (v != 0.f) atomicAdd(&acc3[t], v);
  }
}

__global__ void k_pool3(const float* __restrict__ acc3, float* __restrict__ out, int n_graphs) {
  int g = blockIdx.x * blockDim.x + threadIdx.x;
  if (g < n_graphs) {
    float s = acc3[3 * g] + 1e-16f;
    float p0 = acc3[3 * g + 1] / s, p1 = acc3[3 * g + 2] / s;
    float m = fmaxf(p0, p1);
    float e0 = expf(p0 - m), e1 = expf(p1 - m);
    float d = e0 + e1;
    out[2 * g] = e0 / d;
    out[2 * g + 1] = e1 / d;
  }
}

// ---------------- host ----------------
extern "C" void kernel_launch(void* const* d_in, const int* in_sizes, int n_in,
                              void* d_out, int out_size, void* d_ws, size_t ws_size,
                              hipStream_t stream)
{
  const float* x        = (const float*)d_in[0];
  const int*   edge     = (const int*)d_in[1];
  const int*   batch    = (const int*)d_in[2];
  const float* reduce_w = (const float*)d_in[3];
  const float* reduce_b = (const float*)d_in[4];
  const float* ggc_w    = (const float*)d_in[5];
  const float* w_ih     = (const float*)d_in[6];
  const float* w_hh     = (const float*)d_in[7];
  const float* b_ih     = (const float*)d_in[8];
  const float* b_hh     = (const float*)d_in[9];
  const float* gate_w   = (const float*)d_in[10];
  const float* gate_b   = (const float*)d_in[11];
  const float* out_w    = (const float*)d_in[12];
  const float* out_b    = (const float*)d_in[13];
  float* out = (float*)d_out;

  const int n_nodes  = in_sizes[0] / ANNOT;
  const int E        = in_sizes[1] / 2;
  const int n_graphs = out_size / 2;
  const int* src  = edge;
  const int* dstv = edge + E;
  const int nbuk = (n_nodes + 511) >> 9;

  size_t off = 0;
  auto alloc = [&](size_t bytes) { size_t o = off; off = (off + bytes + 255) & ~(size_t)255; return o; };
  char* w = (char*)d_ws;

  unsigned short* h    = (unsigned short*)(w + alloc((size_t)n_nodes * HID * 2));
  unsigned char*  h8   = (unsigned char*)(w + alloc((size_t)n_nodes * HID));
  unsigned short* aggr = (unsigned short*)(w + alloc((size_t)n_nodes * HID * 2));
  int*   csr_src = (int*)(w + alloc((size_t)E * 4));
  int*   row_ptr = (int*)(w + alloc((size_t)(n_nodes + 1) * 4));
  uint2* rec     = (uint2*)(w + alloc((size_t)E * 8));
  int*   bukCnt  = (int*)(w + alloc((size_t)(nbuk + 1) * 4));
  int*   bukBase = (int*)(w + alloc((size_t)(nbuk + 1) * 4));
  int*   bukCur  = (int*)(w + alloc((size_t)(nbuk + 1) * 4));
  unsigned short* Bpack = (unsigned short*)(w + alloc((size_t)NSTEPS * 8 * 8 * 64 * 8 * 2));
  unsigned short* Wpack = (unsigned short*)(w + alloc((size_t)64 * 64 * 8 * 2));
  float* gl      = (float*)(w + alloc((size_t)n_nodes * 4));
  float* f2      = (float*)(w + alloc((size_t)n_nodes * 2 * 4));
  unsigned* gmax = (unsigned*)(w + alloc(256));
  float* acc3    = (float*)(w + alloc(192 * 4));
  (void)ws_size; (void)n_in;

  hipMemsetAsync(bukCnt, 0, (size_t)(nbuk + 1) * 4, stream);
  hipMemsetAsync(gmax, 0, 256, stream);
  hipMemsetAsync(acc3, 0, 192 * 4, stream);

  const int gN256 = (n_nodes + 255) / 256;
  const int nchunk = (E + PCHUNK - 1) / PCHUNK;

  k_wpack<<<64, 64, 0, stream>>>(reduce_w, Wpack);
  k_reduce<<<(n_nodes + 127) / 128, 256, 0, stream>>>(x, Wpack, reduce_b, h, h8, n_nodes);
  k_bbig<<<dim3(8, 8, NSTEPS), 64, 0, stream>>>(ggc_w, w_ih, w_hh, Bpack);

  k_pcnt<<<1024, 256, 0, stream>>>(dstv, E, bukCnt, nbuk);
  k_bscan<<<1, 1, 0, stream>>>(bukCnt, nbuk, bukBase, bukCur, row_ptr, n_nodes, E);
  k_part<<<nchunk, 256, 0, stream>>>(src, dstv, E, bukCur, rec, nbuk);
  k_csr<<<nbuk, 512, 0, stream>>>(rec, bukBase, row_ptr, csr_src, n_nodes);

  for (int s = 0; s < NSTEPS; ++s) {
    k_aggr<<<(n_nodes + 3) / 4, 256, 0, stream>>>((const uint2*)h8, row_ptr, csr_src, (uint4*)aggr, n_nodes);
    k_gru<<<(n_nodes + 127) / 128, 256, 0, stream>>>(aggr, h, h8, Bpack + (size_t)s * 8 * 8 * 64 * 8, b_ih, b_hh, n_nodes);
  }

  k_pool1<<<gN256, 256, 0, stream>>>(h, batch, gate_w, gate_b, out_w, out_b, gl, f2, gmax, n_nodes);
  k_pool2<<<gN256, 256, 0, stream>>>(gl, f2, batch, gmax, acc3, n_nodes);
  k_pool3<<<1, 64, 0, stream>>>(acc3, out, n_graphs);
}